// Round 9
// baseline (221.379 us; speedup 1.0000x reference)
//
#include <hip/hip_runtime.h>
#include <math.h>

#define BATCH 2
#define SEQ   2048
#define CDIM  1024
#define NHEAD 16
#define HDIM  64
#define TOKS  (BATCH * SEQ)   // 4096

typedef __bf16 bf16x8 __attribute__((ext_vector_type(8)));
typedef __bf16 bf16x2 __attribute__((ext_vector_type(2)));
typedef float  f32x4  __attribute__((ext_vector_type(4)));
typedef float  f32x16 __attribute__((ext_vector_type(16)));

#define MFMA16(a, b, c) __builtin_amdgcn_mfma_f32_16x16x32_bf16(a, b, c, 0, 0, 0)
#define MFMA32(a, b, c) __builtin_amdgcn_mfma_f32_32x32x16_bf16(a, b, c, 0, 0, 0)

// 0.125 * log2(e): folded into Q projection so p = exp2(s) == softmax-exact
#define QSCALE 0.1803368801111204f

__device__ __forceinline__ void gload_lds16(const __bf16* g, __bf16* l) {
    __builtin_amdgcn_global_load_lds(
        (const __attribute__((address_space(1))) unsigned int*)g,
        (__attribute__((address_space(3))) unsigned int*)l, 16, 0, 0);
}

// ---------------------------------------------------------------------------
// Prep: blocks [0,6144): fp32->bf16 convert of q,k,v (2048 blocks each).
//       blocks [6144,7168): W (KxN fp32) -> Wt (NxK bf16) transpose, 4 mats.
// ---------------------------------------------------------------------------
__global__ __launch_bounds__(256) void prep_kernel(
    const float* __restrict__ q, const float* __restrict__ k, const float* __restrict__ v,
    __bf16* __restrict__ qo, __bf16* __restrict__ ko, __bf16* __restrict__ vo,
    const float* __restrict__ W0, const float* __restrict__ W1,
    const float* __restrict__ W2, const float* __restrict__ W3,
    __bf16* __restrict__ T0, __bf16* __restrict__ T1,
    __bf16* __restrict__ T2, __bf16* __restrict__ T3)
{
    __shared__ __bf16 Ts[64][72];
    const int bx = blockIdx.x;
    const int tid = threadIdx.x;

    if (bx < 6144) {
        const int t = bx >> 11;
        const size_t i = ((size_t)(bx & 2047) * 256 + tid) * 8;
        const float* s = t == 0 ? q : (t == 1 ? k : v);
        __bf16* d = t == 0 ? qo : (t == 1 ? ko : vo);
        const float4 x = *(const float4*)&s[i];
        const float4 y = *(const float4*)&s[i + 4];
        bf16x8 o;
        o[0] = (__bf16)x.x; o[1] = (__bf16)x.y; o[2] = (__bf16)x.z; o[3] = (__bf16)x.w;
        o[4] = (__bf16)y.x; o[5] = (__bf16)y.y; o[6] = (__bf16)y.z; o[7] = (__bf16)y.w;
        *(bf16x8*)&d[i] = o;
        return;
    }

    const int t  = bx - 6144;
    const int z  = t >> 8;
    const int ry = (t & 255) >> 4;
    const int rx = t & 15;
    const float* W = z == 0 ? W0 : z == 1 ? W1 : z == 2 ? W2 : W3;
    __bf16* T = z == 0 ? T0 : z == 1 ? T1 : z == 2 ? T2 : T3;
    const int rb = ry * 64, cb = rx * 64;
    const int r = tid >> 4;
    const int c4 = (tid & 15) * 4;
#pragma unroll
    for (int p = 0; p < 4; p++) {
        const int rr = p * 16 + r;
        const float4 w4 = *(const float4*)&W[(size_t)(rb + rr) * CDIM + cb + c4];
        Ts[c4 + 0][rr] = (__bf16)w4.x;
        Ts[c4 + 1][rr] = (__bf16)w4.y;
        Ts[c4 + 2][rr] = (__bf16)w4.z;
        Ts[c4 + 3][rr] = (__bf16)w4.w;
    }
    __syncthreads();
    const int n = tid >> 2;
    const int k16 = (tid & 3) * 16;
    *(bf16x8*)&T[(size_t)(cb + n) * CDIM + rb + k16]     = *(const bf16x8*)&Ts[n][k16];
    *(bf16x8*)&T[(size_t)(cb + n) * CDIM + rb + k16 + 8] = *(const bf16x8*)&Ts[n][k16 + 8];
}

// ---------------------------------------------------------------------------
// Fused QKV projection GEMM, one dispatch, z selects:
//   z=0: Qh = (q@Wq + bq)*QSCALE  -> (B,H,L,D) bf16
//   z=1: Kh = (k@Wk + bk)         -> (B,H,L,D) bf16
//   z=2: Vht = (Wv^T @ v^T + bv)  -> [chan][tok] bf16, NATURAL token order
//
// 512 threads / 8 waves on the 128x128 tile; chunked XCD swizzle (96/XCD).
// ---------------------------------------------------------------------------
__global__ __launch_bounds__(512, 6) void qkv_gemm_kernel(
    const __bf16* __restrict__ qb, const __bf16* __restrict__ kb,
    const __bf16* __restrict__ vb,
    const __bf16* __restrict__ Wqt, const __bf16* __restrict__ Wkt,
    const __bf16* __restrict__ Wvt,
    const float* __restrict__ bq, const float* __restrict__ bk,
    const float* __restrict__ bv,
    __bf16* __restrict__ Qh, __bf16* __restrict__ Kh, __bf16* __restrict__ Vht)
{
    __shared__ __bf16 As[128 * 32];
    __shared__ __bf16 Bs[128 * 32];

    const int lin = blockIdx.x + (blockIdx.y << 3) + (blockIdx.z << 8);
    const int nl  = (lin & 7) * 96 + (lin >> 3);
    const int bx  = nl & 7;
    const int by  = (nl >> 3) & 31;
    const int z   = nl >> 8;

    const __bf16* A    = z == 0 ? qb : z == 1 ? kb : Wvt;
    const __bf16* Bt   = z == 0 ? Wqt : z == 1 ? Wkt : vb;
    const float*  bias = z == 0 ? bq : z == 1 ? bk : bv;

    const int tid  = threadIdx.x;
    const int w    = tid >> 6;     // 0..7
    const int lane = tid & 63;
    const int quad = lane >> 4;
    const int c    = lane & 15;
    const int wm   = w >> 1;       // 0..3: 32-row strip
    const int wn   = w & 1;        // 0..1: 64-col strip
    const int rowBase = (z == 2 ? bx : by) * 128;
    const int colBase = (z == 2 ? by : bx) * 128;

    const int sr = lane >> 2;
    const int sk = (lane & 3) * 8;

    f32x4 acc[2][4];
#pragma unroll
    for (int i = 0; i < 2; i++)
#pragma unroll
        for (int j = 0; j < 4; j++) acc[i][j] = (f32x4){0, 0, 0, 0};

    const __bf16* srcA = A  + (size_t)(rowBase + w * 16 + sr) * CDIM + sk;
    const __bf16* srcB = Bt + (size_t)(colBase + w * 16 + sr) * CDIM + sk;
    __bf16* dstA = &As[w * 16 * 32];
    __bf16* dstB = &Bs[w * 16 * 32];

    for (int k0 = 0; k0 < CDIM; k0 += 32) {
        gload_lds16(srcA + k0, dstA);
        gload_lds16(srcB + k0, dstB);
        __syncthreads();

        bf16x8 af[2], bf[4];
#pragma unroll
        for (int i = 0; i < 2; i++)
            af[i] = *(const bf16x8*)&As[(wm * 32 + i * 16 + c) * 32 + quad * 8];
#pragma unroll
        for (int i = 0; i < 4; i++)
            bf[i] = *(const bf16x8*)&Bs[(wn * 64 + i * 16 + c) * 32 + quad * 8];
#pragma unroll
        for (int mi = 0; mi < 2; mi++)
#pragma unroll
            for (int ni = 0; ni < 4; ni++)
                acc[mi][ni] = MFMA16(af[mi], bf[ni], acc[mi][ni]);
        __syncthreads();
    }

#pragma unroll
    for (int mi = 0; mi < 2; mi++) {
#pragma unroll
        for (int ni = 0; ni < 4; ni++) {
            const int col = colBase + wn * 64 + ni * 16 + c;
#pragma unroll
            for (int r = 0; r < 4; r++) {
                const int row = rowBase + wm * 32 + mi * 16 + quad * 4 + r;
                const float val = acc[mi][ni][r];
                if (z == 2) {
                    Vht[(size_t)row * TOKS + col] = (__bf16)(val + bias[row]);
                } else {
                    const int b = row >> 11, l = row & 2047;
                    const int h = col >> 6,  d = col & 63;
                    const float s = (z == 0) ? QSCALE : 1.0f;
                    __bf16* outp = (z == 0) ? Qh : Kh;
                    outp[((((size_t)b * NHEAD + h) * SEQ) + l) * HDIM + d] =
                        (__bf16)((val + bias[col]) * s);
                }
            }
        }
    }
}

// ---------------------------------------------------------------------------
// Final projection GEMM: out(fp32) = Yb(bf16) @ Wot^T + bo.
// 512 threads / 8 waves on the 128x64 tile; chunked XCD swizzle.
// ---------------------------------------------------------------------------
__global__ __launch_bounds__(512, 4) void out_gemm_kernel(
    const __bf16* __restrict__ A, const __bf16* __restrict__ Bt,
    const float* __restrict__ bias, float* __restrict__ out)
{
    __shared__ __bf16 As[128 * 32];
    __shared__ __bf16 Bs[64 * 32];

    const int lin = blockIdx.x + (blockIdx.y << 4);
    const int nl  = (lin & 7) * 64 + (lin >> 3);
    const int bx  = nl & 15;
    const int by  = nl >> 4;

    const int tid  = threadIdx.x;
    const int w    = tid >> 6;
    const int lane = tid & 63;
    const int quad = lane >> 4;
    const int c    = lane & 15;
    const int wm   = w >> 1;
    const int wn   = w & 1;
    const int rowBase = by * 128;
    const int colBase = bx * 64;
    const int sr = lane >> 2;
    const int sk = (lane & 3) * 8;

    f32x4 acc[2][2];
#pragma unroll
    for (int i = 0; i < 2; i++)
#pragma unroll
        for (int j = 0; j < 2; j++) acc[i][j] = (f32x4){0, 0, 0, 0};

    const __bf16* srcA = A + (size_t)(rowBase + w * 16 + sr) * CDIM + sk;
    const __bf16* srcB = Bt + (size_t)(colBase + (w & 3) * 16 + sr) * CDIM + sk;
    __bf16* dstA = &As[w * 16 * 32];
    __bf16* dstB = &Bs[(w & 3) * 16 * 32];

    for (int k0 = 0; k0 < CDIM; k0 += 32) {
        gload_lds16(srcA + k0, dstA);
        if (w < 4) gload_lds16(srcB + k0, dstB);
        __syncthreads();

        bf16x8 af[2], bf[2];
#pragma unroll
        for (int i = 0; i < 2; i++)
            af[i] = *(const bf16x8*)&As[(wm * 32 + i * 16 + c) * 32 + quad * 8];
#pragma unroll
        for (int i = 0; i < 2; i++)
            bf[i] = *(const bf16x8*)&Bs[(wn * 32 + i * 16 + c) * 32 + quad * 8];
#pragma unroll
        for (int mi = 0; mi < 2; mi++)
#pragma unroll
            for (int ni = 0; ni < 2; ni++)
                acc[mi][ni] = MFMA16(af[mi], bf[ni], acc[mi][ni]);
        __syncthreads();
    }

#pragma unroll
    for (int mi = 0; mi < 2; mi++) {
#pragma unroll
        for (int ni = 0; ni < 2; ni++) {
            const int col = colBase + wn * 32 + ni * 16 + c;
#pragma unroll
            for (int r = 0; r < 4; r++) {
                const int row = rowBase + wm * 32 + mi * 16 + quad * 4 + r;
                out[(size_t)row * CDIM + col] = acc[mi][ni][r] + bias[col];
            }
        }
    }
}

// ---------------------------------------------------------------------------
// Attention v12: fat waves + conflict-free LDS.
// 256 thr / 4 waves = (2 q-strips x 2 key-halves); each wave owns 64 q-rows
// (2 q-groups of 32) and 1024 keys -> every K/V fragment read feeds TWO
// q-groups: LDS read bytes per FLOP halved vs v11.
// LDS: per [buf][stream] K and V tiles stored as 8 chunks of 1 KB + 16 B pad
// (chunk stride 1040 B == 4 banks mod 32) + row-XOR slot swizzle -> both the
// intra-chunk 8-way and the cross-chunk 4-way aliasing are gone (was 5M
// conflict cycles). gload_lds staging, source pre-swizzled (rule #21).
// Compute math identical to verified v8/v10/v11 (swapped QK^T, in-register
// softmax via permlane32_swap, L via ones-MFMA). Split-K combine through
// LDS scratch in lane-contiguous 16 B layout. Grid (32,16), 2 blocks/CU.
// ---------------------------------------------------------------------------
__global__ __launch_bounds__(256, 2) void attn_v12_kernel(
    const __bf16* __restrict__ Qh, const __bf16* __restrict__ Kh,
    const __bf16* __restrict__ Vht, __bf16* __restrict__ Y)
{
    // [buf][stream][K/V][8 chunks x 520 bf16 (1024B data + 16B pad)]
    __shared__ __align__(16) __bf16 lds[2][2][2][8 * 520];   // 66560 B

    const int tid  = threadIdx.x;
    const int w    = tid >> 6;           // 0..3
    const int wq   = w & 1;              // q-strip (64 rows)
    const int kh   = w >> 1;             // key-half (1024 keys)
    const int lane = tid & 63;
    const int l31  = lane & 31;
    const int hi   = lane >> 5;
    const int rr8  = l31 & 7;
    const int cb   = (l31 >> 3) * 520 + rr8 * 64;   // chunk base for frag rows
    const int bh   = blockIdx.x;         // head fastest -> XCD pin
    const int b    = bh >> 4;
    const int h    = bh & 15;
    const int qbase = blockIdx.y * 128 + wq * 64;

    const __bf16* Qg  = Qh + (size_t)bh * SEQ * HDIM;
    const __bf16* KgB = Kh + (size_t)bh * SEQ * HDIM;
    const __bf16* VgB = Vht + (size_t)(h * HDIM) * TOKS + (size_t)b * SEQ;

    // Q B-operand frags for both q-groups
    bf16x8 qf0[4], qf1[4];
#pragma unroll
    for (int ks = 0; ks < 4; ks++) {
        qf0[ks] = *(const bf16x8*)&Qg[(size_t)(qbase + l31) * HDIM + ks * 16 + hi * 8];
        qf1[ks] = *(const bf16x8*)&Qg[(size_t)(qbase + 32 + l31) * HDIM + ks * 16 + hi * 8];
    }

    bf16x8 ones;
#pragma unroll
    for (int j = 0; j < 8; j++) ones[j] = (__bf16)1.0f;

    f32x16 O00, O01, O10, O11, LA0, LA1;
#pragma unroll
    for (int j = 0; j < 16; j++) {
        O00[j] = 0.0f; O01[j] = 0.0f; O10[j] = 0.0f; O11[j] = 0.0f;
        LA0[j] = 0.0f; LA1[j] = 0.0f;
    }

    // staging duty: wave w stages {w=0: K s0, w=1: K s1, w=2: V s0, w=3: V s1}
    const int sidx = w & 1;
    const int iskv = w >> 1;
    const int kr8 = lane >> 3, kc = lane & 7;

#define STAGE(T, bb)                                                          \
    {                                                                         \
        _Pragma("unroll")                                                     \
        for (int jj = 0; jj < 8; jj++) {                                      \
            if (iskv == 0)                                                    \
                gload_lds16(KgB + (size_t)(sidx * 1024 + (T) + 8 * jj + kr8) * HDIM \
                                + ((kc ^ kr8) * 8),                           \
                            &lds[bb][sidx][0][jj * 520]);                     \
            else                                                              \
                gload_lds16(VgB + (size_t)(8 * jj + kr8) * TOKS               \
                                + sidx * 1024 + (T) + ((kc ^ kr8) * 8),       \
                            &lds[bb][sidx][1][jj * 520]);                     \
        }                                                                     \
    }

#define PACK_AF(P, KL, AF)                                                    \
    {                                                                         \
        const int r0 = (KL) * 8;                                              \
        union { bf16x2 v; unsigned int u; } pa, pb, pc, pd;                   \
        pa.v[0] = (__bf16)P[r0 + 0]; pa.v[1] = (__bf16)P[r0 + 1];             \
        pb.v[0] = (__bf16)P[r0 + 2]; pb.v[1] = (__bf16)P[r0 + 3];             \
        pc.v[0] = (__bf16)P[r0 + 4]; pc.v[1] = (__bf16)P[r0 + 5];             \
        pd.v[0] = (__bf16)P[r0 + 6]; pd.v[1] = (__bf16)P[r0 + 7];             \
        asm volatile("v_permlane32_swap_b32 %0, %1" : "+v"(pa.u), "+v"(pc.u)); \
        asm volatile("v_permlane32_swap_b32 %0, %1" : "+v"(pb.u), "+v"(pd.u)); \
        AF.u[0] = pa.u; AF.u[1] = pb.u; AF.u[2] = pc.u; AF.u[3] = pd.u;       \
    }

    STAGE(0, 0);
    __syncthreads();

    int buf = 0;
    for (int t0 = 0; t0 < 1024; t0 += 64) {
        const int tn = t0 + 64;
        if (tn < 1024) {
            if (buf == 0) STAGE(tn, 1) else STAGE(tn, 0)
        }

        const __bf16* ldsK = &lds[buf][kh][0][0];
        const __bf16* ldsV = &lds[buf][kh][1][0];

#pragma unroll
        for (int kt = 0; kt < 2; kt++) {
            // K frags (shared by both q-groups); rows = keys kt*32 + l31
            const bf16x8 kf0 = *(const bf16x8*)&ldsK[kt * 2080 + cb + (((0 + hi) ^ rr8) * 8)];
            const bf16x8 kf1 = *(const bf16x8*)&ldsK[kt * 2080 + cb + (((2 + hi) ^ rr8) * 8)];
            const bf16x8 kf2 = *(const bf16x8*)&ldsK[kt * 2080 + cb + (((4 + hi) ^ rr8) * 8)];
            const bf16x8 kf3 = *(const bf16x8*)&ldsK[kt * 2080 + cb + (((6 + hi) ^ rr8) * 8)];

            f32x16 s0, s1;
#pragma unroll
            for (int j = 0; j < 16; j++) { s0[j] = 0.0f; s1[j] = 0.0f; }
            s0 = MFMA32(kf0, qf0[0], s0);
            s1 = MFMA32(kf0, qf1[0], s1);
            s0 = MFMA32(kf1, qf0[1], s0);
            s1 = MFMA32(kf1, qf1[1], s1);
            s0 = MFMA32(kf2, qf0[2], s0);
            s1 = MFMA32(kf2, qf1[2], s1);
            s0 = MFMA32(kf3, qf0[3], s0);
            s1 = MFMA32(kf3, qf1[3], s1);

            float p0[16], p1[16];
#pragma unroll
            for (int j = 0; j < 16; j++) {
                p0[j] = __builtin_amdgcn_exp2f(s0[j]);
                p1[j] = __builtin_amdgcn_exp2f(s1[j]);
            }

#pragma unroll
            for (int kl = 0; kl < 2; kl++) {
                union AFU { unsigned int u[4]; bf16x8 v; } af0, af1;
                PACK_AF(p0, kl, af0);
                PACK_AF(p1, kl, af1);
                const int sv = (((kt * 4 + kl * 2 + hi) ^ rr8) * 8);
                const bf16x8 vf0 = *(const bf16x8*)&ldsV[cb + sv];
                const bf16x8 vf1 = *(const bf16x8*)&ldsV[2080 + cb + sv];
                __builtin_amdgcn_s_setprio(1);
                LA0 = MFMA32(af0.v, ones, LA0);
                O00 = MFMA32(af0.v, vf0, O00);
                O01 = MFMA32(af0.v, vf1, O01);
                LA1 = MFMA32(af1.v, ones, LA1);
                O10 = MFMA32(af1.v, vf0, O10);
                O11 = MFMA32(af1.v, vf1, O11);
                __builtin_amdgcn_s_setprio(0);
            }
        }

        __syncthreads();
        buf ^= 1;
    }
#undef STAGE

    // ---- split-K combine via LDS scratch (tiles dead after final barrier)
    float* scr = (float*)&lds[0][0][0][0];   // 48 KB used
    const int wl = wq * 64 + lane;           // 0..127

#define SPILL(OP, OPI)                                                        \
    { union { f32x16 v; f32x4 q[4]; } tt; tt.v = OP;                          \
      _Pragma("unroll")                                                       \
      for (int part = 0; part < 4; part++)                                    \
          *(f32x4*)&scr[(((OPI) * 4 + part) * 128 + wl) * 4] = tt.q[part]; }

#define MERGE(OP, OPI)                                                        \
    { union { f32x16 v; f32x4 q[4]; } tt; tt.v = OP;                          \
      _Pragma("unroll")                                                       \
      for (int part = 0; part < 4; part++)                                    \
          tt.q[part] += *(const f32x4*)&scr[(((OPI) * 4 + part) * 128 + wl) * 4]; \
      OP = tt.v; }

    if (kh == 1) {
        SPILL(O00, 0); SPILL(O01, 1); SPILL(O10, 2);
        SPILL(O11, 3); SPILL(LA0, 4); SPILL(LA1, 5);
    }
    __syncthreads();
    if (kh == 0) {
        MERGE(O00, 0); MERGE(O01, 1); MERGE(O10, 2);
        MERGE(O11, 3); MERGE(LA0, 4); MERGE(LA1, 5);

        __bf16* Yb = Y + (size_t)b * SEQ * CDIM;
#pragma unroll
        for (int reg = 0; reg < 16; reg++) {
            const int qrow = (reg & 3) + 8 * (reg >> 2) + 4 * hi;
            const float i0 = 1.0f / LA0[reg];
            const float i1 = 1.0f / LA1[reg];
            __bf16* yp0 = Yb + (size_t)(qbase + qrow) * CDIM + h * HDIM + l31;
            __bf16* yp1 = Yb + (size_t)(qbase + 32 + qrow) * CDIM + h * HDIM + l31;
            yp0[0]  = (__bf16)(O00[reg] * i0);
            yp0[32] = (__bf16)(O01[reg] * i0);
            yp1[0]  = (__bf16)(O10[reg] * i1);
            yp1[32] = (__bf16)(O11[reg] * i1);
        }
    }
#undef SPILL
#undef MERGE
#undef PACK_AF
}

// ---------------------------------------------------------------------------

extern "C" void kernel_launch(void* const* d_in, const int* in_sizes, int n_in,
                              void* d_out, int out_size, void* d_ws, size_t ws_size,
                              hipStream_t stream)
{
    const float* q  = (const float*)d_in[0];
    const float* k  = (const float*)d_in[1];
    const float* v  = (const float*)d_in[2];
    const float* Wq = (const float*)d_in[3];
    const float* bq = (const float*)d_in[4];
    const float* Wk = (const float*)d_in[5];
    const float* bk = (const float*)d_in[6];
    const float* Wv = (const float*)d_in[7];
    const float* bv = (const float*)d_in[8];
    const float* Wo = (const float*)d_in[9];
    const float* bo = (const float*)d_in[10];
    float* out = (float*)d_out;

    const size_t MAT = (size_t)TOKS * CDIM;
    const size_t WN  = (size_t)CDIM * CDIM;

    __bf16* p   = (__bf16*)d_ws;
    __bf16* qb  = p; p += MAT;
    __bf16* kb  = p; p += MAT;
    __bf16* vb  = p; p += MAT;
    __bf16* Wqt = p; p += WN;
    __bf16* Wkt = p; p += WN;
    __bf16* Wvt = p; p += WN;
    __bf16* Wot = p; p += WN;
    __bf16* Qh  = p; p += MAT;   // (B,H,L,D), scaled by QSCALE
    __bf16* Kh  = p; p += MAT;   // (B,H,L,D)
    __bf16* Vht = p; p += MAT;   // [chan][tok], natural order
    __bf16* Yb  = qb;            // alias: qb dead after QKV GEMM

    prep_kernel<<<dim3(7168), dim3(256), 0, stream>>>(
        q, k, v, qb, kb, vb, Wq, Wk, Wv, Wo, Wqt, Wkt, Wvt, Wot);

    qkv_gemm_kernel<<<dim3(8, 32, 3), dim3(512), 0, stream>>>(
        qb, kb, vb, Wqt, Wkt, Wvt, bq, bk, bv, Qh, Kh, Vht);

    attn_v12_kernel<<<dim3(BATCH * NHEAD, SEQ / 128), dim3(256), 0, stream>>>(Qh, Kh, Vht, Yb);

    out_gemm_kernel<<<dim3(16, 32), dim3(512), 0, stream>>>(Yb, Wot, bo, out);
}

// Round 10
// 216.876 us; speedup vs baseline: 1.0208x; 1.0208x over previous
//
#include <hip/hip_runtime.h>
#include <math.h>

#define BATCH 2
#define SEQ   2048
#define CDIM  1024
#define NHEAD 16
#define HDIM  64
#define TOKS  (BATCH * SEQ)   // 4096

typedef __bf16 bf16x8 __attribute__((ext_vector_type(8)));
typedef __bf16 bf16x2 __attribute__((ext_vector_type(2)));
typedef float  f32x4  __attribute__((ext_vector_type(4)));
typedef float  f32x16 __attribute__((ext_vector_type(16)));

#define MFMA16(a, b, c) __builtin_amdgcn_mfma_f32_16x16x32_bf16(a, b, c, 0, 0, 0)
#define MFMA32(a, b, c) __builtin_amdgcn_mfma_f32_32x32x16_bf16(a, b, c, 0, 0, 0)

// 0.125 * log2(e): folded into Q projection so p = exp2(s) == softmax-exact
#define QSCALE 0.1803368801111204f

__device__ __forceinline__ void gload_lds16(const __bf16* g, __bf16* l) {
    __builtin_amdgcn_global_load_lds(
        (const __attribute__((address_space(1))) unsigned int*)g,
        (__attribute__((address_space(3))) unsigned int*)l, 16, 0, 0);
}

// ---------------------------------------------------------------------------
// Prep: blocks [0,6144): fp32->bf16 convert of q,k,v (2048 blocks each).
//       blocks [6144,7168): W (KxN fp32) -> Wt (NxK bf16) transpose, 4 mats.
// ---------------------------------------------------------------------------
__global__ __launch_bounds__(256) void prep_kernel(
    const float* __restrict__ q, const float* __restrict__ k, const float* __restrict__ v,
    __bf16* __restrict__ qo, __bf16* __restrict__ ko, __bf16* __restrict__ vo,
    const float* __restrict__ W0, const float* __restrict__ W1,
    const float* __restrict__ W2, const float* __restrict__ W3,
    __bf16* __restrict__ T0, __bf16* __restrict__ T1,
    __bf16* __restrict__ T2, __bf16* __restrict__ T3)
{
    __shared__ __bf16 Ts[64][72];
    const int bx = blockIdx.x;
    const int tid = threadIdx.x;

    if (bx < 6144) {
        const int t = bx >> 11;
        const size_t i = ((size_t)(bx & 2047) * 256 + tid) * 8;
        const float* s = t == 0 ? q : (t == 1 ? k : v);
        __bf16* d = t == 0 ? qo : (t == 1 ? ko : vo);
        const float4 x = *(const float4*)&s[i];
        const float4 y = *(const float4*)&s[i + 4];
        bf16x8 o;
        o[0] = (__bf16)x.x; o[1] = (__bf16)x.y; o[2] = (__bf16)x.z; o[3] = (__bf16)x.w;
        o[4] = (__bf16)y.x; o[5] = (__bf16)y.y; o[6] = (__bf16)y.z; o[7] = (__bf16)y.w;
        *(bf16x8*)&d[i] = o;
        return;
    }

    const int t  = bx - 6144;
    const int z  = t >> 8;
    const int ry = (t & 255) >> 4;
    const int rx = t & 15;
    const float* W = z == 0 ? W0 : z == 1 ? W1 : z == 2 ? W2 : W3;
    __bf16* T = z == 0 ? T0 : z == 1 ? T1 : z == 2 ? T2 : T3;
    const int rb = ry * 64, cb = rx * 64;
    const int r = tid >> 4;
    const int c4 = (tid & 15) * 4;
#pragma unroll
    for (int p = 0; p < 4; p++) {
        const int rr = p * 16 + r;
        const float4 w4 = *(const float4*)&W[(size_t)(rb + rr) * CDIM + cb + c4];
        Ts[c4 + 0][rr] = (__bf16)w4.x;
        Ts[c4 + 1][rr] = (__bf16)w4.y;
        Ts[c4 + 2][rr] = (__bf16)w4.z;
        Ts[c4 + 3][rr] = (__bf16)w4.w;
    }
    __syncthreads();
    const int n = tid >> 2;
    const int k16 = (tid & 3) * 16;
    *(bf16x8*)&T[(size_t)(cb + n) * CDIM + rb + k16]     = *(const bf16x8*)&Ts[n][k16];
    *(bf16x8*)&T[(size_t)(cb + n) * CDIM + rb + k16 + 8] = *(const bf16x8*)&Ts[n][k16 + 8];
}

// ---------------------------------------------------------------------------
// Fused QKV projection GEMM, one dispatch, z selects:
//   z=0: Qh = (q@Wq + bq)*QSCALE  -> (B,H,L,D) bf16
//   z=1: Kh = (k@Wk + bk)         -> (B,H,L,D) bf16
//   z=2: Vht = (Wv^T @ v^T + bv)  -> [chan][tok] bf16, NATURAL token order
//
// 512 threads / 8 waves on the 128x128 tile; chunked XCD swizzle (96/XCD).
// ---------------------------------------------------------------------------
__global__ __launch_bounds__(512, 6) void qkv_gemm_kernel(
    const __bf16* __restrict__ qb, const __bf16* __restrict__ kb,
    const __bf16* __restrict__ vb,
    const __bf16* __restrict__ Wqt, const __bf16* __restrict__ Wkt,
    const __bf16* __restrict__ Wvt,
    const float* __restrict__ bq, const float* __restrict__ bk,
    const float* __restrict__ bv,
    __bf16* __restrict__ Qh, __bf16* __restrict__ Kh, __bf16* __restrict__ Vht)
{
    __shared__ __bf16 As[128 * 32];
    __shared__ __bf16 Bs[128 * 32];

    const int lin = blockIdx.x + (blockIdx.y << 3) + (blockIdx.z << 8);
    const int nl  = (lin & 7) * 96 + (lin >> 3);
    const int bx  = nl & 7;
    const int by  = (nl >> 3) & 31;
    const int z   = nl >> 8;

    const __bf16* A    = z == 0 ? qb : z == 1 ? kb : Wvt;
    const __bf16* Bt   = z == 0 ? Wqt : z == 1 ? Wkt : vb;
    const float*  bias = z == 0 ? bq : z == 1 ? bk : bv;

    const int tid  = threadIdx.x;
    const int w    = tid >> 6;     // 0..7
    const int lane = tid & 63;
    const int quad = lane >> 4;
    const int c    = lane & 15;
    const int wm   = w >> 1;       // 0..3: 32-row strip
    const int wn   = w & 1;        // 0..1: 64-col strip
    const int rowBase = (z == 2 ? bx : by) * 128;
    const int colBase = (z == 2 ? by : bx) * 128;

    const int sr = lane >> 2;
    const int sk = (lane & 3) * 8;

    f32x4 acc[2][4];
#pragma unroll
    for (int i = 0; i < 2; i++)
#pragma unroll
        for (int j = 0; j < 4; j++) acc[i][j] = (f32x4){0, 0, 0, 0};

    const __bf16* srcA = A  + (size_t)(rowBase + w * 16 + sr) * CDIM + sk;
    const __bf16* srcB = Bt + (size_t)(colBase + w * 16 + sr) * CDIM + sk;
    __bf16* dstA = &As[w * 16 * 32];
    __bf16* dstB = &Bs[w * 16 * 32];

    for (int k0 = 0; k0 < CDIM; k0 += 32) {
        gload_lds16(srcA + k0, dstA);
        gload_lds16(srcB + k0, dstB);
        __syncthreads();

        bf16x8 af[2], bf[4];
#pragma unroll
        for (int i = 0; i < 2; i++)
            af[i] = *(const bf16x8*)&As[(wm * 32 + i * 16 + c) * 32 + quad * 8];
#pragma unroll
        for (int i = 0; i < 4; i++)
            bf[i] = *(const bf16x8*)&Bs[(wn * 64 + i * 16 + c) * 32 + quad * 8];
#pragma unroll
        for (int mi = 0; mi < 2; mi++)
#pragma unroll
            for (int ni = 0; ni < 4; ni++)
                acc[mi][ni] = MFMA16(af[mi], bf[ni], acc[mi][ni]);
        __syncthreads();
    }

#pragma unroll
    for (int mi = 0; mi < 2; mi++) {
#pragma unroll
        for (int ni = 0; ni < 4; ni++) {
            const int col = colBase + wn * 64 + ni * 16 + c;
#pragma unroll
            for (int r = 0; r < 4; r++) {
                const int row = rowBase + wm * 32 + mi * 16 + quad * 4 + r;
                const float val = acc[mi][ni][r];
                if (z == 2) {
                    Vht[(size_t)row * TOKS + col] = (__bf16)(val + bias[row]);
                } else {
                    const int b = row >> 11, l = row & 2047;
                    const int h = col >> 6,  d = col & 63;
                    const float s = (z == 0) ? QSCALE : 1.0f;
                    __bf16* outp = (z == 0) ? Qh : Kh;
                    outp[((((size_t)b * NHEAD + h) * SEQ) + l) * HDIM + d] =
                        (__bf16)((val + bias[col]) * s);
                }
            }
        }
    }
}

// ---------------------------------------------------------------------------
// Final projection GEMM: out(fp32) = Yb(bf16) @ Wot^T + bo.
// 512 threads / 8 waves on the 128x64 tile; chunked XCD swizzle.
// ---------------------------------------------------------------------------
__global__ __launch_bounds__(512, 4) void out_gemm_kernel(
    const __bf16* __restrict__ A, const __bf16* __restrict__ Bt,
    const float* __restrict__ bias, float* __restrict__ out)
{
    __shared__ __bf16 As[128 * 32];
    __shared__ __bf16 Bs[64 * 32];

    const int lin = blockIdx.x + (blockIdx.y << 4);
    const int nl  = (lin & 7) * 64 + (lin >> 3);
    const int bx  = nl & 15;
    const int by  = nl >> 4;

    const int tid  = threadIdx.x;
    const int w    = tid >> 6;
    const int lane = tid & 63;
    const int quad = lane >> 4;
    const int c    = lane & 15;
    const int wm   = w >> 1;
    const int wn   = w & 1;
    const int rowBase = by * 128;
    const int colBase = bx * 64;
    const int sr = lane >> 2;
    const int sk = (lane & 3) * 8;

    f32x4 acc[2][2];
#pragma unroll
    for (int i = 0; i < 2; i++)
#pragma unroll
        for (int j = 0; j < 2; j++) acc[i][j] = (f32x4){0, 0, 0, 0};

    const __bf16* srcA = A + (size_t)(rowBase + w * 16 + sr) * CDIM + sk;
    const __bf16* srcB = Bt + (size_t)(colBase + (w & 3) * 16 + sr) * CDIM + sk;
    __bf16* dstA = &As[w * 16 * 32];
    __bf16* dstB = &Bs[(w & 3) * 16 * 32];

    for (int k0 = 0; k0 < CDIM; k0 += 32) {
        gload_lds16(srcA + k0, dstA);
        if (w < 4) gload_lds16(srcB + k0, dstB);
        __syncthreads();

        bf16x8 af[2], bf[2];
#pragma unroll
        for (int i = 0; i < 2; i++)
            af[i] = *(const bf16x8*)&As[(wm * 32 + i * 16 + c) * 32 + quad * 8];
#pragma unroll
        for (int i = 0; i < 2; i++)
            bf[i] = *(const bf16x8*)&Bs[(wn * 32 + i * 16 + c) * 32 + quad * 8];
#pragma unroll
        for (int mi = 0; mi < 2; mi++)
#pragma unroll
            for (int ni = 0; ni < 2; ni++)
                acc[mi][ni] = MFMA16(af[mi], bf[ni], acc[mi][ni]);
        __syncthreads();
    }

#pragma unroll
    for (int mi = 0; mi < 2; mi++) {
#pragma unroll
        for (int ni = 0; ni < 2; ni++) {
            const int col = colBase + wn * 32 + ni * 16 + c;
#pragma unroll
            for (int r = 0; r < 4; r++) {
                const int row = rowBase + wm * 32 + mi * 16 + quad * 4 + r;
                out[(size_t)row * CDIM + col] = acc[mi][ni][r] + bias[col];
            }
        }
    }
}

// ---------------------------------------------------------------------------
// Attention v13 = v12 minus the ones-MFMA L (was 8 of 40 MFMA32/step = 20%
// of matrix-pipe cycles). After swapped-QK, p is lane-local per q, so
// L[q] = sum of the lane's own f32 p values: 64 v_add_f32/step (VALU,
// the cooler pipe) replace 8 MFMA32. Per-lane Lp covers this hi-half's
// keys; epilogue does Lp += shfl_xor(Lp,32) then a per-reg shfl broadcast
// (32 bpermutes, once). Split-K L spill shrinks to 2 scalars per lane.
// Rest identical to v12: 256 thr / 4 waves = 2 q-strips x 2 key-halves,
// 64 q-rows/wave, chunk-padded XOR-swizzled LDS, gload_lds staging,
// in-register softmax via permlane32_swap. Grid (32,16), 2 blocks/CU.
// ---------------------------------------------------------------------------
__global__ __launch_bounds__(256, 2) void attn_v13_kernel(
    const __bf16* __restrict__ Qh, const __bf16* __restrict__ Kh,
    const __bf16* __restrict__ Vht, __bf16* __restrict__ Y)
{
    // [buf][stream][K/V][8 chunks x 520 bf16 (1024B data + 16B pad)]
    __shared__ __align__(16) __bf16 lds[2][2][2][8 * 520];   // 66560 B

    const int tid  = threadIdx.x;
    const int w    = tid >> 6;           // 0..3
    const int wq   = w & 1;              // q-strip (64 rows)
    const int kh   = w >> 1;             // key-half (1024 keys)
    const int lane = tid & 63;
    const int l31  = lane & 31;
    const int hi   = lane >> 5;
    const int rr8  = l31 & 7;
    const int cb   = (l31 >> 3) * 520 + rr8 * 64;   // chunk base for frag rows
    const int bh   = blockIdx.x;         // head fastest -> XCD pin
    const int b    = bh >> 4;
    const int h    = bh & 15;
    const int qbase = blockIdx.y * 128 + wq * 64;

    const __bf16* Qg  = Qh + (size_t)bh * SEQ * HDIM;
    const __bf16* KgB = Kh + (size_t)bh * SEQ * HDIM;
    const __bf16* VgB = Vht + (size_t)(h * HDIM) * TOKS + (size_t)b * SEQ;

    // Q B-operand frags for both q-groups
    bf16x8 qf0[4], qf1[4];
#pragma unroll
    for (int ks = 0; ks < 4; ks++) {
        qf0[ks] = *(const bf16x8*)&Qg[(size_t)(qbase + l31) * HDIM + ks * 16 + hi * 8];
        qf1[ks] = *(const bf16x8*)&Qg[(size_t)(qbase + 32 + l31) * HDIM + ks * 16 + hi * 8];
    }

    f32x16 O00, O01, O10, O11;
#pragma unroll
    for (int j = 0; j < 16; j++) {
        O00[j] = 0.0f; O01[j] = 0.0f; O10[j] = 0.0f; O11[j] = 0.0f;
    }
    float Lp0 = 0.0f, Lp1 = 0.0f;   // per-lane L partial (this hi-half's keys)

    // staging duty: wave w stages {w=0: K s0, w=1: K s1, w=2: V s0, w=3: V s1}
    const int sidx = w & 1;
    const int iskv = w >> 1;
    const int kr8 = lane >> 3, kc = lane & 7;

#define STAGE(T, bb)                                                          \
    {                                                                         \
        _Pragma("unroll")                                                     \
        for (int jj = 0; jj < 8; jj++) {                                      \
            if (iskv == 0)                                                    \
                gload_lds16(KgB + (size_t)(sidx * 1024 + (T) + 8 * jj + kr8) * HDIM \
                                + ((kc ^ kr8) * 8),                           \
                            &lds[bb][sidx][0][jj * 520]);                     \
            else                                                              \
                gload_lds16(VgB + (size_t)(8 * jj + kr8) * TOKS               \
                                + sidx * 1024 + (T) + ((kc ^ kr8) * 8),       \
                            &lds[bb][sidx][1][jj * 520]);                     \
        }                                                                     \
    }

#define PACK_AF(P, KL, AF)                                                    \
    {                                                                         \
        const int r0 = (KL) * 8;                                              \
        union { bf16x2 v; unsigned int u; } pa, pb, pc, pd;                   \
        pa.v[0] = (__bf16)P[r0 + 0]; pa.v[1] = (__bf16)P[r0 + 1];             \
        pb.v[0] = (__bf16)P[r0 + 2]; pb.v[1] = (__bf16)P[r0 + 3];             \
        pc.v[0] = (__bf16)P[r0 + 4]; pc.v[1] = (__bf16)P[r0 + 5];             \
        pd.v[0] = (__bf16)P[r0 + 6]; pd.v[1] = (__bf16)P[r0 + 7];             \
        asm volatile("v_permlane32_swap_b32 %0, %1" : "+v"(pa.u), "+v"(pc.u)); \
        asm volatile("v_permlane32_swap_b32 %0, %1" : "+v"(pb.u), "+v"(pd.u)); \
        AF.u[0] = pa.u; AF.u[1] = pb.u; AF.u[2] = pc.u; AF.u[3] = pd.u;       \
    }

    STAGE(0, 0);
    __syncthreads();

    int buf = 0;
    for (int t0 = 0; t0 < 1024; t0 += 64) {
        const int tn = t0 + 64;
        if (tn < 1024) {
            if (buf == 0) STAGE(tn, 1) else STAGE(tn, 0)
        }

        const __bf16* ldsK = &lds[buf][kh][0][0];
        const __bf16* ldsV = &lds[buf][kh][1][0];

#pragma unroll
        for (int kt = 0; kt < 2; kt++) {
            // K frags (shared by both q-groups); rows = keys kt*32 + l31
            const bf16x8 kf0 = *(const bf16x8*)&ldsK[kt * 2080 + cb + (((0 + hi) ^ rr8) * 8)];
            const bf16x8 kf1 = *(const bf16x8*)&ldsK[kt * 2080 + cb + (((2 + hi) ^ rr8) * 8)];
            const bf16x8 kf2 = *(const bf16x8*)&ldsK[kt * 2080 + cb + (((4 + hi) ^ rr8) * 8)];
            const bf16x8 kf3 = *(const bf16x8*)&ldsK[kt * 2080 + cb + (((6 + hi) ^ rr8) * 8)];

            f32x16 s0, s1;
#pragma unroll
            for (int j = 0; j < 16; j++) { s0[j] = 0.0f; s1[j] = 0.0f; }
            s0 = MFMA32(kf0, qf0[0], s0);
            s1 = MFMA32(kf0, qf1[0], s1);
            s0 = MFMA32(kf1, qf0[1], s0);
            s1 = MFMA32(kf1, qf1[1], s1);
            s0 = MFMA32(kf2, qf0[2], s0);
            s1 = MFMA32(kf2, qf1[2], s1);
            s0 = MFMA32(kf3, qf0[3], s0);
            s1 = MFMA32(kf3, qf1[3], s1);

            float p0[16], p1[16];
#pragma unroll
            for (int j = 0; j < 16; j++) {
                p0[j] = __builtin_amdgcn_exp2f(s0[j]);
                p1[j] = __builtin_amdgcn_exp2f(s1[j]);
            }
            // L partials on the VALU (replaces the ones-MFMA: -20% MFMA work)
#pragma unroll
            for (int j = 0; j < 16; j++) {
                Lp0 += p0[j];
                Lp1 += p1[j];
            }

#pragma unroll
            for (int kl = 0; kl < 2; kl++) {
                union AFU { unsigned int u[4]; bf16x8 v; } af0, af1;
                PACK_AF(p0, kl, af0);
                PACK_AF(p1, kl, af1);
                const int sv = (((kt * 4 + kl * 2 + hi) ^ rr8) * 8);
                const bf16x8 vf0 = *(const bf16x8*)&ldsV[cb + sv];
                const bf16x8 vf1 = *(const bf16x8*)&ldsV[2080 + cb + sv];
                __builtin_amdgcn_s_setprio(1);
                O00 = MFMA32(af0.v, vf0, O00);
                O01 = MFMA32(af0.v, vf1, O01);
                O10 = MFMA32(af1.v, vf0, O10);
                O11 = MFMA32(af1.v, vf1, O11);
                __builtin_amdgcn_s_setprio(0);
            }
        }

        __syncthreads();
        buf ^= 1;
    }
#undef STAGE

    // ---- split-K combine via LDS scratch (tiles dead after final barrier)
    float* scr  = (float*)&lds[0][0][0][0];    // 32 KB: O spills
    float* scrL = scr + 8192;                  // 1 KB: L partials
    const int wl = wq * 64 + lane;             // 0..127

#define SPILL(OP, OPI)                                                        \
    { union { f32x16 v; f32x4 q[4]; } tt; tt.v = OP;                          \
      _Pragma("unroll")                                                       \
      for (int part = 0; part < 4; part++)                                    \
          *(f32x4*)&scr[(((OPI) * 4 + part) * 128 + wl) * 4] = tt.q[part]; }

#define MERGE(OP, OPI)                                                        \
    { union { f32x16 v; f32x4 q[4]; } tt; tt.v = OP;                          \
      _Pragma("unroll")                                                       \
      for (int part = 0; part < 4; part++)                                    \
          tt.q[part] += *(const f32x4*)&scr[(((OPI) * 4 + part) * 128 + wl) * 4]; \
      OP = tt.v; }

    if (kh == 1) {
        SPILL(O00, 0); SPILL(O01, 1); SPILL(O10, 2); SPILL(O11, 3);
        scrL[wl]       = Lp0;
        scrL[128 + wl] = Lp1;
    }
    __syncthreads();
    if (kh == 0) {
        MERGE(O00, 0); MERGE(O01, 1); MERGE(O10, 2); MERGE(O11, 3);
        Lp0 += scrL[wl];
        Lp1 += scrL[128 + wl];

        // full row-sums: add the partner hi-half, then invert (lane = q)
        const float Lt0 = Lp0 + __shfl_xor(Lp0, 32);
        const float Lt1 = Lp1 + __shfl_xor(Lp1, 32);
        const float inv0 = 1.0f / Lt0;
        const float inv1 = 1.0f / Lt1;

        __bf16* Yb = Y + (size_t)b * SEQ * CDIM;
#pragma unroll
        for (int reg = 0; reg < 16; reg++) {
            const int qrow = (reg & 3) + 8 * (reg >> 2) + 4 * hi;
            const float i0 = __shfl(inv0, qrow);   // lane qrow holds q=qbase+qrow
            const float i1 = __shfl(inv1, qrow);
            __bf16* yp0 = Yb + (size_t)(qbase + qrow) * CDIM + h * HDIM + l31;
            __bf16* yp1 = Yb + (size_t)(qbase + 32 + qrow) * CDIM + h * HDIM + l31;
            yp0[0]  = (__bf16)(O00[reg] * i0);
            yp0[32] = (__bf16)(O01[reg] * i0);
            yp1[0]  = (__bf16)(O10[reg] * i1);
            yp1[32] = (__bf16)(O11[reg] * i1);
        }
    }
#undef SPILL
#undef MERGE
#undef PACK_AF
}

// ---------------------------------------------------------------------------

extern "C" void kernel_launch(void* const* d_in, const int* in_sizes, int n_in,
                              void* d_out, int out_size, void* d_ws, size_t ws_size,
                              hipStream_t stream)
{
    const float* q  = (const float*)d_in[0];
    const float* k  = (const float*)d_in[1];
    const float* v  = (const float*)d_in[2];
    const float* Wq = (const float*)d_in[3];
    const float* bq = (const float*)d_in[4];
    const float* Wk = (const float*)d_in[5];
    const float* bk = (const float*)d_in[6];
    const float* Wv = (const float*)d_in[7];
    const float* bv = (const float*)d_in[8];
    const float* Wo = (const float*)d_in[9];
    const float* bo = (const float*)d_in[10];
    float* out = (float*)d_out;

    const size_t MAT = (size_t)TOKS * CDIM;
    const size_t WN  = (size_t)CDIM * CDIM;

    __bf16* p   = (__bf16*)d_ws;
    __bf16* qb  = p; p += MAT;
    __bf16* kb  = p; p += MAT;
    __bf16* vb  = p; p += MAT;
    __bf16* Wqt = p; p += WN;
    __bf16* Wkt = p; p += WN;
    __bf16* Wvt = p; p += WN;
    __bf16* Wot = p; p += WN;
    __bf16* Qh  = p; p += MAT;   // (B,H,L,D), scaled by QSCALE
    __bf16* Kh  = p; p += MAT;   // (B,H,L,D)
    __bf16* Vht = p; p += MAT;   // [chan][tok], natural order
    __bf16* Yb  = qb;            // alias: qb dead after QKV GEMM

    prep_kernel<<<dim3(7168), dim3(256), 0, stream>>>(
        q, k, v, qb, kb, vb, Wq, Wk, Wv, Wo, Wqt, Wkt, Wvt, Wot);

    qkv_gemm_kernel<<<dim3(8, 32, 3), dim3(512), 0, stream>>>(
        qb, kb, vb, Wqt, Wkt, Wvt, bq, bk, bv, Qh, Kh, Vht);

    attn_v13_kernel<<<dim3(BATCH * NHEAD, SEQ / 128), dim3(256), 0, stream>>>(Qh, Kh, Vht, Yb);

    out_gemm_kernel<<<dim3(16, 32), dim3(512), 0, stream>>>(Yb, Wot, bo, out);
}

// Round 11
// 214.673 us; speedup vs baseline: 1.0312x; 1.0103x over previous
//
#include <hip/hip_runtime.h>
#include <math.h>

#define BATCH 2
#define SEQ   2048
#define CDIM  1024
#define NHEAD 16
#define HDIM  64
#define TOKS  (BATCH * SEQ)   // 4096

typedef __bf16 bf16x8 __attribute__((ext_vector_type(8)));
typedef __bf16 bf16x2 __attribute__((ext_vector_type(2)));
typedef float  f32x4  __attribute__((ext_vector_type(4)));
typedef float  f32x16 __attribute__((ext_vector_type(16)));

#define MFMA16(a, b, c) __builtin_amdgcn_mfma_f32_16x16x32_bf16(a, b, c, 0, 0, 0)
#define MFMA32(a, b, c) __builtin_amdgcn_mfma_f32_32x32x16_bf16(a, b, c, 0, 0, 0)

// 0.125 * log2(e): folded into Q projection so p = exp2(s) == softmax-exact
#define QSCALE 0.1803368801111204f

__device__ __forceinline__ void gload_lds16(const __bf16* g, __bf16* l) {
    __builtin_amdgcn_global_load_lds(
        (const __attribute__((address_space(1))) unsigned int*)g,
        (__attribute__((address_space(3))) unsigned int*)l, 16, 0, 0);
}

// ---------------------------------------------------------------------------
// Prep: blocks [0,6144): fp32->bf16 convert of q,k,v (2048 blocks each).
//       blocks [6144,7168): W (KxN fp32) -> Wt (NxK bf16) transpose, 4 mats.
// ---------------------------------------------------------------------------
__global__ __launch_bounds__(256) void prep_kernel(
    const float* __restrict__ q, const float* __restrict__ k, const float* __restrict__ v,
    __bf16* __restrict__ qo, __bf16* __restrict__ ko, __bf16* __restrict__ vo,
    const float* __restrict__ W0, const float* __restrict__ W1,
    const float* __restrict__ W2, const float* __restrict__ W3,
    __bf16* __restrict__ T0, __bf16* __restrict__ T1,
    __bf16* __restrict__ T2, __bf16* __restrict__ T3)
{
    __shared__ __bf16 Ts[64][72];
    const int bx = blockIdx.x;
    const int tid = threadIdx.x;

    if (bx < 6144) {
        const int t = bx >> 11;
        const size_t i = ((size_t)(bx & 2047) * 256 + tid) * 8;
        const float* s = t == 0 ? q : (t == 1 ? k : v);
        __bf16* d = t == 0 ? qo : (t == 1 ? ko : vo);
        const float4 x = *(const float4*)&s[i];
        const float4 y = *(const float4*)&s[i + 4];
        bf16x8 o;
        o[0] = (__bf16)x.x; o[1] = (__bf16)x.y; o[2] = (__bf16)x.z; o[3] = (__bf16)x.w;
        o[4] = (__bf16)y.x; o[5] = (__bf16)y.y; o[6] = (__bf16)y.z; o[7] = (__bf16)y.w;
        *(bf16x8*)&d[i] = o;
        return;
    }

    const int t  = bx - 6144;
    const int z  = t >> 8;
    const int ry = (t & 255) >> 4;
    const int rx = t & 15;
    const float* W = z == 0 ? W0 : z == 1 ? W1 : z == 2 ? W2 : W3;
    __bf16* T = z == 0 ? T0 : z == 1 ? T1 : z == 2 ? T2 : T3;
    const int rb = ry * 64, cb = rx * 64;
    const int r = tid >> 4;
    const int c4 = (tid & 15) * 4;
#pragma unroll
    for (int p = 0; p < 4; p++) {
        const int rr = p * 16 + r;
        const float4 w4 = *(const float4*)&W[(size_t)(rb + rr) * CDIM + cb + c4];
        Ts[c4 + 0][rr] = (__bf16)w4.x;
        Ts[c4 + 1][rr] = (__bf16)w4.y;
        Ts[c4 + 2][rr] = (__bf16)w4.z;
        Ts[c4 + 3][rr] = (__bf16)w4.w;
    }
    __syncthreads();
    const int n = tid >> 2;
    const int k16 = (tid & 3) * 16;
    *(bf16x8*)&T[(size_t)(cb + n) * CDIM + rb + k16]     = *(const bf16x8*)&Ts[n][k16];
    *(bf16x8*)&T[(size_t)(cb + n) * CDIM + rb + k16 + 8] = *(const bf16x8*)&Ts[n][k16 + 8];
}

// ---------------------------------------------------------------------------
// Fused QKV projection GEMM, one dispatch, z selects:
//   z=0: Qh = (q@Wq + bq)*QSCALE  -> (B,H,L,D) bf16
//   z=1: Kh = (k@Wk + bk)         -> (B,H,L,D) bf16
//   z=2: Vht = (Wv^T @ v^T + bv)  -> [chan][tok] bf16, NATURAL token order
//
// 512 threads / 8 waves on the 128x128 tile; chunked XCD swizzle (96/XCD).
// v3: DOUBLE-BUFFERED prefetch loop (T3 minimum-2-phase, m248v2): issue
// next K-slice's global_load_lds BEFORE computing the current slice, ONE
// barrier per K-step (was 2) -> staging latency hides under the 16 MFMAs.
// LDS 32 KB -> still 3 blocks/CU.
// ---------------------------------------------------------------------------
__global__ __launch_bounds__(512, 6) void qkv_gemm_kernel(
    const __bf16* __restrict__ qb, const __bf16* __restrict__ kb,
    const __bf16* __restrict__ vb,
    const __bf16* __restrict__ Wqt, const __bf16* __restrict__ Wkt,
    const __bf16* __restrict__ Wvt,
    const float* __restrict__ bq, const float* __restrict__ bk,
    const float* __restrict__ bv,
    __bf16* __restrict__ Qh, __bf16* __restrict__ Kh, __bf16* __restrict__ Vht)
{
    __shared__ __bf16 As[2][128 * 32];
    __shared__ __bf16 Bs[2][128 * 32];

    const int lin = blockIdx.x + (blockIdx.y << 3) + (blockIdx.z << 8);
    const int nl  = (lin & 7) * 96 + (lin >> 3);
    const int bx  = nl & 7;
    const int by  = (nl >> 3) & 31;
    const int z   = nl >> 8;

    const __bf16* A    = z == 0 ? qb : z == 1 ? kb : Wvt;
    const __bf16* Bt   = z == 0 ? Wqt : z == 1 ? Wkt : vb;
    const float*  bias = z == 0 ? bq : z == 1 ? bk : bv;

    const int tid  = threadIdx.x;
    const int w    = tid >> 6;     // 0..7
    const int lane = tid & 63;
    const int quad = lane >> 4;
    const int c    = lane & 15;
    const int wm   = w >> 1;       // 0..3: 32-row strip
    const int wn   = w & 1;        // 0..1: 64-col strip
    const int rowBase = (z == 2 ? bx : by) * 128;
    const int colBase = (z == 2 ? by : bx) * 128;

    const int sr = lane >> 2;
    const int sk = (lane & 3) * 8;

    f32x4 acc[2][4];
#pragma unroll
    for (int i = 0; i < 2; i++)
#pragma unroll
        for (int j = 0; j < 4; j++) acc[i][j] = (f32x4){0, 0, 0, 0};

    const __bf16* srcA = A  + (size_t)(rowBase + w * 16 + sr) * CDIM + sk;
    const __bf16* srcB = Bt + (size_t)(colBase + w * 16 + sr) * CDIM + sk;
    const int dstOff = w * 16 * 32;

#define QSTAGE(K0, BB)                                   \
    {                                                    \
        gload_lds16(srcA + (K0), &As[BB][dstOff]);       \
        gload_lds16(srcB + (K0), &Bs[BB][dstOff]);       \
    }

    QSTAGE(0, 0);
    __syncthreads();

    int buf = 0;
    for (int k0 = 0; k0 < CDIM; k0 += 32) {
        if (k0 + 32 < CDIM) {
            if (buf == 0) QSTAGE(k0 + 32, 1) else QSTAGE(k0 + 32, 0)
        }

        bf16x8 af[2], bf[4];
#pragma unroll
        for (int i = 0; i < 2; i++)
            af[i] = *(const bf16x8*)&As[buf][(wm * 32 + i * 16 + c) * 32 + quad * 8];
#pragma unroll
        for (int i = 0; i < 4; i++)
            bf[i] = *(const bf16x8*)&Bs[buf][(wn * 64 + i * 16 + c) * 32 + quad * 8];
#pragma unroll
        for (int mi = 0; mi < 2; mi++)
#pragma unroll
            for (int ni = 0; ni < 4; ni++)
                acc[mi][ni] = MFMA16(af[mi], bf[ni], acc[mi][ni]);
        __syncthreads();
        buf ^= 1;
    }
#undef QSTAGE

#pragma unroll
    for (int mi = 0; mi < 2; mi++) {
#pragma unroll
        for (int ni = 0; ni < 4; ni++) {
            const int col = colBase + wn * 64 + ni * 16 + c;
#pragma unroll
            for (int r = 0; r < 4; r++) {
                const int row = rowBase + wm * 32 + mi * 16 + quad * 4 + r;
                const float val = acc[mi][ni][r];
                if (z == 2) {
                    Vht[(size_t)row * TOKS + col] = (__bf16)(val + bias[row]);
                } else {
                    const int b = row >> 11, l = row & 2047;
                    const int h = col >> 6,  d = col & 63;
                    const float s = (z == 0) ? QSCALE : 1.0f;
                    __bf16* outp = (z == 0) ? Qh : Kh;
                    outp[((((size_t)b * NHEAD + h) * SEQ) + l) * HDIM + d] =
                        (__bf16)((val + bias[col]) * s);
                }
            }
        }
    }
}

// ---------------------------------------------------------------------------
// Final projection GEMM: out(fp32) = Yb(bf16) @ Wot^T + bo.
// 512 threads / 8 waves on the 128x64 tile; chunked XCD swizzle.
// v3: double-buffered prefetch loop, one barrier per K-step (see qkv v3).
// ---------------------------------------------------------------------------
__global__ __launch_bounds__(512, 4) void out_gemm_kernel(
    const __bf16* __restrict__ A, const __bf16* __restrict__ Bt,
    const float* __restrict__ bias, float* __restrict__ out)
{
    __shared__ __bf16 As[2][128 * 32];
    __shared__ __bf16 Bs[2][64 * 32];

    const int lin = blockIdx.x + (blockIdx.y << 4);
    const int nl  = (lin & 7) * 64 + (lin >> 3);
    const int bx  = nl & 15;
    const int by  = nl >> 4;

    const int tid  = threadIdx.x;
    const int w    = tid >> 6;
    const int lane = tid & 63;
    const int quad = lane >> 4;
    const int c    = lane & 15;
    const int wm   = w >> 1;
    const int wn   = w & 1;
    const int rowBase = by * 128;
    const int colBase = bx * 64;
    const int sr = lane >> 2;
    const int sk = (lane & 3) * 8;

    f32x4 acc[2][2];
#pragma unroll
    for (int i = 0; i < 2; i++)
#pragma unroll
        for (int j = 0; j < 2; j++) acc[i][j] = (f32x4){0, 0, 0, 0};

    const __bf16* srcA = A + (size_t)(rowBase + w * 16 + sr) * CDIM + sk;
    const __bf16* srcB = Bt + (size_t)(colBase + (w & 3) * 16 + sr) * CDIM + sk;
    const int dstAoff = w * 16 * 32;
    const int dstBoff = (w & 3) * 16 * 32;

#define OSTAGE(K0, BB)                                           \
    {                                                            \
        gload_lds16(srcA + (K0), &As[BB][dstAoff]);              \
        if (w < 4) gload_lds16(srcB + (K0), &Bs[BB][dstBoff]);   \
    }

    OSTAGE(0, 0);
    __syncthreads();

    int buf = 0;
    for (int k0 = 0; k0 < CDIM; k0 += 32) {
        if (k0 + 32 < CDIM) {
            if (buf == 0) OSTAGE(k0 + 32, 1) else OSTAGE(k0 + 32, 0)
        }

        bf16x8 af[2], bf[2];
#pragma unroll
        for (int i = 0; i < 2; i++)
            af[i] = *(const bf16x8*)&As[buf][(wm * 32 + i * 16 + c) * 32 + quad * 8];
#pragma unroll
        for (int i = 0; i < 2; i++)
            bf[i] = *(const bf16x8*)&Bs[buf][(wn * 32 + i * 16 + c) * 32 + quad * 8];
#pragma unroll
        for (int mi = 0; mi < 2; mi++)
#pragma unroll
            for (int ni = 0; ni < 2; ni++)
                acc[mi][ni] = MFMA16(af[mi], bf[ni], acc[mi][ni]);
        __syncthreads();
        buf ^= 1;
    }
#undef OSTAGE

#pragma unroll
    for (int mi = 0; mi < 2; mi++) {
#pragma unroll
        for (int ni = 0; ni < 2; ni++) {
            const int col = colBase + wn * 32 + ni * 16 + c;
#pragma unroll
            for (int r = 0; r < 4; r++) {
                const int row = rowBase + wm * 32 + mi * 16 + quad * 4 + r;
                out[(size_t)row * CDIM + col] = acc[mi][ni][r] + bias[col];
            }
        }
    }
}

// ---------------------------------------------------------------------------
// Attention v13 (unchanged): 256 thr / 4 waves = 2 q-strips x 2 key-halves,
// 64 q-rows/wave via 32x32x16 MFMA, swapped QK^T, in-register softmax
// (permlane32_swap), VALU L partials, chunk-padded XOR-swizzled LDS,
// gload_lds staging, split-K combine via LDS. Grid (32,16), 2 blocks/CU.
// Plateau ~48.7 us across 7 structural variants (pipe convoy).
// ---------------------------------------------------------------------------
__global__ __launch_bounds__(256, 2) void attn_v13_kernel(
    const __bf16* __restrict__ Qh, const __bf16* __restrict__ Kh,
    const __bf16* __restrict__ Vht, __bf16* __restrict__ Y)
{
    // [buf][stream][K/V][8 chunks x 520 bf16 (1024B data + 16B pad)]
    __shared__ __align__(16) __bf16 lds[2][2][2][8 * 520];   // 66560 B

    const int tid  = threadIdx.x;
    const int w    = tid >> 6;           // 0..3
    const int wq   = w & 1;              // q-strip (64 rows)
    const int kh   = w >> 1;             // key-half (1024 keys)
    const int lane = tid & 63;
    const int l31  = lane & 31;
    const int hi   = lane >> 5;
    const int rr8  = l31 & 7;
    const int cb   = (l31 >> 3) * 520 + rr8 * 64;   // chunk base for frag rows
    const int bh   = blockIdx.x;         // head fastest -> XCD pin
    const int b    = bh >> 4;
    const int h    = bh & 15;
    const int qbase = blockIdx.y * 128 + wq * 64;

    const __bf16* Qg  = Qh + (size_t)bh * SEQ * HDIM;
    const __bf16* KgB = Kh + (size_t)bh * SEQ * HDIM;
    const __bf16* VgB = Vht + (size_t)(h * HDIM) * TOKS + (size_t)b * SEQ;

    // Q B-operand frags for both q-groups
    bf16x8 qf0[4], qf1[4];
#pragma unroll
    for (int ks = 0; ks < 4; ks++) {
        qf0[ks] = *(const bf16x8*)&Qg[(size_t)(qbase + l31) * HDIM + ks * 16 + hi * 8];
        qf1[ks] = *(const bf16x8*)&Qg[(size_t)(qbase + 32 + l31) * HDIM + ks * 16 + hi * 8];
    }

    f32x16 O00, O01, O10, O11;
#pragma unroll
    for (int j = 0; j < 16; j++) {
        O00[j] = 0.0f; O01[j] = 0.0f; O10[j] = 0.0f; O11[j] = 0.0f;
    }
    float Lp0 = 0.0f, Lp1 = 0.0f;   // per-lane L partial (this hi-half's keys)

    // staging duty: wave w stages {w=0: K s0, w=1: K s1, w=2: V s0, w=3: V s1}
    const int sidx = w & 1;
    const int iskv = w >> 1;
    const int kr8 = lane >> 3, kc = lane & 7;

#define STAGE(T, bb)                                                          \
    {                                                                         \
        _Pragma("unroll")                                                     \
        for (int jj = 0; jj < 8; jj++) {                                      \
            if (iskv == 0)                                                    \
                gload_lds16(KgB + (size_t)(sidx * 1024 + (T) + 8 * jj + kr8) * HDIM \
                                + ((kc ^ kr8) * 8),                           \
                            &lds[bb][sidx][0][jj * 520]);                     \
            else                                                              \
                gload_lds16(VgB + (size_t)(8 * jj + kr8) * TOKS               \
                                + sidx * 1024 + (T) + ((kc ^ kr8) * 8),       \
                            &lds[bb][sidx][1][jj * 520]);                     \
        }                                                                     \
    }

#define PACK_AF(P, KL, AF)                                                    \
    {                                                                         \
        const int r0 = (KL) * 8;                                              \
        union { bf16x2 v; unsigned int u; } pa, pb, pc, pd;                   \
        pa.v[0] = (__bf16)P[r0 + 0]; pa.v[1] = (__bf16)P[r0 + 1];             \
        pb.v[0] = (__bf16)P[r0 + 2]; pb.v[1] = (__bf16)P[r0 + 3];             \
        pc.v[0] = (__bf16)P[r0 + 4]; pc.v[1] = (__bf16)P[r0 + 5];             \
        pd.v[0] = (__bf16)P[r0 + 6]; pd.v[1] = (__bf16)P[r0 + 7];             \
        asm volatile("v_permlane32_swap_b32 %0, %1" : "+v"(pa.u), "+v"(pc.u)); \
        asm volatile("v_permlane32_swap_b32 %0, %1" : "+v"(pb.u), "+v"(pd.u)); \
        AF.u[0] = pa.u; AF.u[1] = pb.u; AF.u[2] = pc.u; AF.u[3] = pd.u;       \
    }

    STAGE(0, 0);
    __syncthreads();

    int buf = 0;
    for (int t0 = 0; t0 < 1024; t0 += 64) {
        const int tn = t0 + 64;
        if (tn < 1024) {
            if (buf == 0) STAGE(tn, 1) else STAGE(tn, 0)
        }

        const __bf16* ldsK = &lds[buf][kh][0][0];
        const __bf16* ldsV = &lds[buf][kh][1][0];

#pragma unroll
        for (int kt = 0; kt < 2; kt++) {
            // K frags (shared by both q-groups); rows = keys kt*32 + l31
            const bf16x8 kf0 = *(const bf16x8*)&ldsK[kt * 2080 + cb + (((0 + hi) ^ rr8) * 8)];
            const bf16x8 kf1 = *(const bf16x8*)&ldsK[kt * 2080 + cb + (((2 + hi) ^ rr8) * 8)];
            const bf16x8 kf2 = *(const bf16x8*)&ldsK[kt * 2080 + cb + (((4 + hi) ^ rr8) * 8)];
            const bf16x8 kf3 = *(const bf16x8*)&ldsK[kt * 2080 + cb + (((6 + hi) ^ rr8) * 8)];

            f32x16 s0, s1;
#pragma unroll
            for (int j = 0; j < 16; j++) { s0[j] = 0.0f; s1[j] = 0.0f; }
            s0 = MFMA32(kf0, qf0[0], s0);
            s1 = MFMA32(kf0, qf1[0], s1);
            s0 = MFMA32(kf1, qf0[1], s0);
            s1 = MFMA32(kf1, qf1[1], s1);
            s0 = MFMA32(kf2, qf0[2], s0);
            s1 = MFMA32(kf2, qf1[2], s1);
            s0 = MFMA32(kf3, qf0[3], s0);
            s1 = MFMA32(kf3, qf1[3], s1);

            float p0[16], p1[16];
#pragma unroll
            for (int j = 0; j < 16; j++) {
                p0[j] = __builtin_amdgcn_exp2f(s0[j]);
                p1[j] = __builtin_amdgcn_exp2f(s1[j]);
            }
            // L partials on the VALU (replaces the ones-MFMA)
#pragma unroll
            for (int j = 0; j < 16; j++) {
                Lp0 += p0[j];
                Lp1 += p1[j];
            }

#pragma unroll
            for (int kl = 0; kl < 2; kl++) {
                union AFU { unsigned int u[4]; bf16x8 v; } af0, af1;
                PACK_AF(p0, kl, af0);
                PACK_AF(p1, kl, af1);
                const int sv = (((kt * 4 + kl * 2 + hi) ^ rr8) * 8);
                const bf16x8 vf0 = *(const bf16x8*)&ldsV[cb + sv];
                const bf16x8 vf1 = *(const bf16x8*)&ldsV[2080 + cb + sv];
                __builtin_amdgcn_s_setprio(1);
                O00 = MFMA32(af0.v, vf0, O00);
                O01 = MFMA32(af0.v, vf1, O01);
                O10 = MFMA32(af1.v, vf0, O10);
                O11 = MFMA32(af1.v, vf1, O11);
                __builtin_amdgcn_s_setprio(0);
            }
        }

        __syncthreads();
        buf ^= 1;
    }
#undef STAGE

    // ---- split-K combine via LDS scratch (tiles dead after final barrier)
    float* scr  = (float*)&lds[0][0][0][0];    // 32 KB: O spills
    float* scrL = scr + 8192;                  // 1 KB: L partials
    const int wl = wq * 64 + lane;             // 0..127

#define SPILL(OP, OPI)                                                        \
    { union { f32x16 v; f32x4 q[4]; } tt; tt.v = OP;                          \
      _Pragma("unroll")                                                       \
      for (int part = 0; part < 4; part++)                                    \
          *(f32x4*)&scr[(((OPI) * 4 + part) * 128 + wl) * 4] = tt.q[part]; }

#define MERGE(OP, OPI)                                                        \
    { union { f32x16 v; f32x4 q[4]; } tt; tt.v = OP;                          \
      _Pragma("unroll")                                                       \
      for (int part = 0; part < 4; part++)                                    \
          tt.q[part] += *(const f32x4*)&scr[(((OPI) * 4 + part) * 128 + wl) * 4]; \
      OP = tt.v; }

    if (kh == 1) {
        SPILL(O00, 0); SPILL(O01, 1); SPILL(O10, 2); SPILL(O11, 3);
        scrL[wl]       = Lp0;
        scrL[128 + wl] = Lp1;
    }
    __syncthreads();
    if (kh == 0) {
        MERGE(O00, 0); MERGE(O01, 1); MERGE(O10, 2); MERGE(O11, 3);
        Lp0 += scrL[wl];
        Lp1 += scrL[128 + wl];

        // full row-sums: add the partner hi-half, then invert (lane = q)
        const float Lt0 = Lp0 + __shfl_xor(Lp0, 32);
        const float Lt1 = Lp1 + __shfl_xor(Lp1, 32);
        const float inv0 = 1.0f / Lt0;
        const float inv1 = 1.0f / Lt1;

        __bf16* Yb = Y + (size_t)b * SEQ * CDIM;
#pragma unroll
        for (int reg = 0; reg < 16; reg++) {
            const int qrow = (reg & 3) + 8 * (reg >> 2) + 4 * hi;
            const float i0 = __shfl(inv0, qrow);   // lane qrow holds q=qbase+qrow
            const float i1 = __shfl(inv1, qrow);
            __bf16* yp0 = Yb + (size_t)(qbase + qrow) * CDIM + h * HDIM + l31;
            __bf16* yp1 = Yb + (size_t)(qbase + 32 + qrow) * CDIM + h * HDIM + l31;
            yp0[0]  = (__bf16)(O00[reg] * i0);
            yp0[32] = (__bf16)(O01[reg] * i0);
            yp1[0]  = (__bf16)(O10[reg] * i1);
            yp1[32] = (__bf16)(O11[reg] * i1);
        }
    }
#undef SPILL
#undef MERGE
#undef PACK_AF
}

// ---------------------------------------------------------------------------

extern "C" void kernel_launch(void* const* d_in, const int* in_sizes, int n_in,
                              void* d_out, int out_size, void* d_ws, size_t ws_size,
                              hipStream_t stream)
{
    const float* q  = (const float*)d_in[0];
    const float* k  = (const float*)d_in[1];
    const float* v  = (const float*)d_in[2];
    const float* Wq = (const float*)d_in[3];
    const float* bq = (const float*)d_in[4];
    const float* Wk = (const float*)d_in[5];
    const float* bk = (const float*)d_in[6];
    const float* Wv = (const float*)d_in[7];
    const float* bv = (const float*)d_in[8];
    const float* Wo = (const float*)d_in[9];
    const float* bo = (const float*)d_in[10];
    float* out = (float*)d_out;

    const size_t MAT = (size_t)TOKS * CDIM;
    const size_t WN  = (size_t)CDIM * CDIM;

    __bf16* p   = (__bf16*)d_ws;
    __bf16* qb  = p; p += MAT;
    __bf16* kb  = p; p += MAT;
    __bf16* vb  = p; p += MAT;
    __bf16* Wqt = p; p += WN;
    __bf16* Wkt = p; p += WN;
    __bf16* Wvt = p; p += WN;
    __bf16* Wot = p; p += WN;
    __bf16* Qh  = p; p += MAT;   // (B,H,L,D), scaled by QSCALE
    __bf16* Kh  = p; p += MAT;   // (B,H,L,D)
    __bf16* Vht = p; p += MAT;   // [chan][tok], natural order
    __bf16* Yb  = qb;            // alias: qb dead after QKV GEMM

    prep_kernel<<<dim3(7168), dim3(256), 0, stream>>>(
        q, k, v, qb, kb, vb, Wq, Wk, Wv, Wo, Wqt, Wkt, Wvt, Wot);

    qkv_gemm_kernel<<<dim3(8, 32, 3), dim3(512), 0, stream>>>(
        qb, kb, vb, Wqt, Wkt, Wvt, bq, bk, bv, Qh, Kh, Vht);

    attn_v13_kernel<<<dim3(BATCH * NHEAD, SEQ / 128), dim3(256), 0, stream>>>(Qh, Kh, Vht, Yb);

    out_gemm_kernel<<<dim3(16, 32), dim3(512), 0, stream>>>(Yb, Wot, bo, out);
}